// Round 9
// baseline (74.808 us; speedup 1.0000x reference)
//
#include <hip/hip_runtime.h>
#include <math.h>

// Problem constants (from setup_inputs)
#define D 1024
#define M 8192
#define N 16384
#define EPS 1e-8

#define IN_BLOCKS 1024               // input blocks, 16 rows each  (16*1024 = 16384)
#define EM_BLOCKS 1024               // embed blocks,  8 rows each  ( 8*1024 =  8192)
#define GRID1 (IN_BLOCKS + EM_BLOCKS) // 2048 -> 8 blocks/CU -> 32 waves/CU
#define IN_ROWS 16
#define EM_ROWS 8

#define CG 64                        // K2 column groups (16 cols each)
#define RG 8                         // K2 row groups (128 rows each)
#define GRID2 (CG * RG)              // 512 blocks

// ws layout:
//   pSign [IN_BLOCKS][D] f32   (4 MB)
//   pS    [EM_BLOCKS][D] f32   (4 MB)
//   pQ    [EM_BLOCKS][D] f32   (4 MB)
//   sgn2/se2/qq2 [RG][D] f64   (64 KB each)
//   counter  int  (zeroed by K1 — memset nodes cost ~5 us)

__global__ __launch_bounds__(256) void stream_kernel(const float* __restrict__ input,
                                                     const float* __restrict__ embed,
                                                     float* __restrict__ pSign,
                                                     float* __restrict__ pS,
                                                     float* __restrict__ pQ,
                                                     int* __restrict__ counter) {
    const int b = blockIdx.x;
    const int t = threadIdx.x;
    const int col = t * 4;

    if (b == 0 && t == 0) *counter = 0;  // visible to K2 via kernel-boundary ordering

    if (b < IN_BLOCKS) {
        const float4* src = reinterpret_cast<const float4*>(input + (size_t)b * IN_ROWS * D + col);
        float s0 = 0.f, s1 = 0.f, s2 = 0.f, s3 = 0.f;
        float4 v[8];
#pragma unroll
        for (int half = 0; half < 2; ++half) {
#pragma unroll
            for (int j = 0; j < 8; ++j)                 // 8 independent loads in flight
                v[j] = src[(size_t)(half * 8 + j) * (D / 4)];
#pragma unroll
            for (int j = 0; j < 8; ++j) {
                s0 += (v[j].x > 0.f ? 1.f : 0.f) - (v[j].x < 0.f ? 1.f : 0.f);
                s1 += (v[j].y > 0.f ? 1.f : 0.f) - (v[j].y < 0.f ? 1.f : 0.f);
                s2 += (v[j].z > 0.f ? 1.f : 0.f) - (v[j].z < 0.f ? 1.f : 0.f);
                s3 += (v[j].w > 0.f ? 1.f : 0.f) - (v[j].w < 0.f ? 1.f : 0.f);
            }
        }
        *reinterpret_cast<float4*>(pSign + (size_t)b * D + col) = make_float4(s0, s1, s2, s3);
    } else {
        const int e = b - IN_BLOCKS;
        const float4* src = reinterpret_cast<const float4*>(embed + (size_t)e * EM_ROWS * D + col);
        float4 s = make_float4(0.f, 0.f, 0.f, 0.f);
        float4 q = make_float4(0.f, 0.f, 0.f, 0.f);
        float4 v[8];
#pragma unroll
        for (int j = 0; j < 8; ++j)                     // 8 independent loads in flight
            v[j] = src[(size_t)j * (D / 4)];
#pragma unroll
        for (int j = 0; j < 8; ++j) {
            s.x += v[j].x; s.y += v[j].y; s.z += v[j].z; s.w += v[j].w;
            q.x += v[j].x * v[j].x; q.y += v[j].y * v[j].y;
            q.z += v[j].z * v[j].z; q.w += v[j].w * v[j].w;
        }
        *reinterpret_cast<float4*>(pS + (size_t)e * D + col) = s;
        *reinterpret_cast<float4*>(pQ + (size_t)e * D + col) = q;
    }
}

// K2: 512 blocks = 64 col-groups x 8 row-groups. Each block reduces a
// 128-row x 16-col stripe of each partial matrix (coalesced 64B segments,
// 8-deep batched loads). Last block (ticket) folds [RG][D]x3 -> scalar.
__global__ __launch_bounds__(256) void reduce_kernel(const float* __restrict__ pSign,
                                                     const float* __restrict__ pS,
                                                     const float* __restrict__ pQ,
                                                     double* __restrict__ sgn2,
                                                     double* __restrict__ se2,
                                                     double* __restrict__ qq2,
                                                     int* __restrict__ counter,
                                                     float* __restrict__ out) {
    const int t = threadIdx.x;
    const int cg = blockIdx.x >> 3;      // 0..63
    const int rg = blockIdx.x & 7;       // 0..7
    const int c = t & 15;                // col within group
    const int g = t >> 4;                // 0..15 row stripe within rgroup
    const int d = cg * 16 + c;
    const int row0 = rg * 128 + g;       // rows row0 + k*16, k=0..7

    float vs[8], ve[8], vq[8];
#pragma unroll
    for (int k = 0; k < 8; ++k) vs[k] = pSign[(size_t)(row0 + k * 16) * D + d];
#pragma unroll
    for (int k = 0; k < 8; ++k) ve[k] = pS[(size_t)(row0 + k * 16) * D + d];
#pragma unroll
    for (int k = 0; k < 8; ++k) vq[k] = pQ[(size_t)(row0 + k * 16) * D + d];

    double sgn = 0.0, se = 0.0, qq = 0.0;
#pragma unroll
    for (int k = 0; k < 8; ++k) { sgn += (double)vs[k]; se += (double)ve[k]; qq += (double)vq[k]; }

    // fold the 4 row-stripes per wave (lanes differing by 16, 32)
    sgn += __shfl_xor(sgn, 16); sgn += __shfl_xor(sgn, 32);
    se  += __shfl_xor(se, 16);  se  += __shfl_xor(se, 32);
    qq  += __shfl_xor(qq, 16);  qq  += __shfl_xor(qq, 32);

    __shared__ double ls[3][4][16];
    const int wid = t >> 6;
    const int lane = t & 63;
    if (lane < 16) { ls[0][wid][lane] = sgn; ls[1][wid][lane] = se; ls[2][wid][lane] = qq; }
    __syncthreads();

    if (t < 16) {
        double S = ls[0][0][t] + ls[0][1][t] + ls[0][2][t] + ls[0][3][t];
        double E = ls[1][0][t] + ls[1][1][t] + ls[1][2][t] + ls[1][3][t];
        double Q = ls[2][0][t] + ls[2][1][t] + ls[2][2][t] + ls[2][3][t];
        sgn2[(size_t)rg * D + cg * 16 + t] = S;
        se2[(size_t)rg * D + cg * 16 + t] = E;
        qq2[(size_t)rg * D + cg * 16 + t] = Q;
    }

    // ---- ticket: last finishing block computes the scalar ----
    __threadfence();
    __syncthreads();
    __shared__ int isLast;
    if (t == 0) {
        int old = __hip_atomic_fetch_add(counter, 1, __ATOMIC_ACQ_REL,
                                         __HIP_MEMORY_SCOPE_AGENT);
        isLast = (old == GRID2 - 1);
    }
    __syncthreads();
    if (!isLast) return;
    __threadfence();

    double acc = 0.0;
#pragma unroll
    for (int rep = 0; rep < 4; ++rep) {
        const int dd = t + rep * 256;
        double S = 0.0, E = 0.0, Q = 0.0;
#pragma unroll
        for (int r = 0; r < RG; ++r) {
            S += sgn2[(size_t)r * D + dd];
            E += se2[(size_t)r * D + dd];
            Q += qq2[(size_t)r * D + dd];
        }
        // per-column term sum: (s_e / (sqrt(M)*max(n2,eps))) * signcount
        acc += (E / (90.50966799187809 * fmax(sqrt(Q), EPS))) * S;
    }

    for (int off = 32; off > 0; off >>= 1) acc += __shfl_down(acc, off);
    __shared__ double wsum[4];
    if (lane == 0) wsum[wid] = acc;
    __syncthreads();
    if (t == 0) out[0] = (float)(wsum[0] + wsum[1] + wsum[2] + wsum[3]);
}

extern "C" void kernel_launch(void* const* d_in, const int* in_sizes, int n_in,
                              void* d_out, int out_size, void* d_ws, size_t ws_size,
                              hipStream_t stream) {
    const float* input = (const float*)d_in[0];   // [N, D]
    const float* embed = (const float*)d_in[1];   // [M, D]
    float* out = (float*)d_out;

    char* ws = (char*)d_ws;
    float* pSign = (float*)ws;                                        // 4 MB
    float* pS = pSign + (size_t)IN_BLOCKS * D;                        // 4 MB
    float* pQ = pS + (size_t)EM_BLOCKS * D;                           // 4 MB
    double* sgn2 = (double*)(pQ + (size_t)EM_BLOCKS * D);             // RG*D f64
    double* se2 = sgn2 + (size_t)RG * D;
    double* qq2 = se2 + (size_t)RG * D;
    int* counter = (int*)(qq2 + (size_t)RG * D);

    stream_kernel<<<GRID1, 256, 0, stream>>>(input, embed, pSign, pS, pQ, counter);
    reduce_kernel<<<GRID2, 256, 0, stream>>>(pSign, pS, pQ, sgn2, se2, qq2, counter, out);
}

// Round 10
// 57.527 us; speedup vs baseline: 1.3004x; 1.3004x over previous
//
#include <hip/hip_runtime.h>
#include <math.h>

// Problem constants (from setup_inputs)
#define D 1024
#define M 8192
#define N 16384
#define EPS 1e-8

#define IN_BLOCKS 1024               // input blocks, 16 rows each  (16*1024 = 16384)
#define EM_BLOCKS 1024               // embed blocks,  8 rows each  ( 8*1024 =  8192)
#define GRID1 (IN_BLOCKS + EM_BLOCKS) // 2048 -> 8 blocks/CU -> 32 waves/CU
#define IN_ROWS 16
#define EM_ROWS 8

#define CG 64                        // K2 column groups (16 cols each)
#define RG 8                         // K2 row groups (128 rows each)
#define GRID2 (CG * RG)              // 512 blocks

// ws layout:
//   pSign [IN_BLOCKS][D] f32   (4 MB)
//   pS    [EM_BLOCKS][D] f32   (4 MB)
//   pQ    [EM_BLOCKS][D] f32   (4 MB)
//   sgn2/se2/qq2 [RG][D] f64   (64 KB each)  -- published via agent-scope atomics
//   counter  int  (zeroed by K1 — memset nodes cost ~5 us)

__global__ __launch_bounds__(256) void stream_kernel(const float* __restrict__ input,
                                                     const float* __restrict__ embed,
                                                     float* __restrict__ pSign,
                                                     float* __restrict__ pS,
                                                     float* __restrict__ pQ,
                                                     int* __restrict__ counter) {
    const int b = blockIdx.x;
    const int t = threadIdx.x;
    const int col = t * 4;

    if (b == 0 && t == 0) *counter = 0;  // visible to K2 via kernel-boundary ordering

    if (b < IN_BLOCKS) {
        const float4* src = reinterpret_cast<const float4*>(input + (size_t)b * IN_ROWS * D + col);
        float s0 = 0.f, s1 = 0.f, s2 = 0.f, s3 = 0.f;
        float4 v[8];
#pragma unroll
        for (int half = 0; half < 2; ++half) {
#pragma unroll
            for (int j = 0; j < 8; ++j)                 // 8 independent loads in flight
                v[j] = src[(size_t)(half * 8 + j) * (D / 4)];
#pragma unroll
            for (int j = 0; j < 8; ++j) {
                s0 += (v[j].x > 0.f ? 1.f : 0.f) - (v[j].x < 0.f ? 1.f : 0.f);
                s1 += (v[j].y > 0.f ? 1.f : 0.f) - (v[j].y < 0.f ? 1.f : 0.f);
                s2 += (v[j].z > 0.f ? 1.f : 0.f) - (v[j].z < 0.f ? 1.f : 0.f);
                s3 += (v[j].w > 0.f ? 1.f : 0.f) - (v[j].w < 0.f ? 1.f : 0.f);
            }
        }
        *reinterpret_cast<float4*>(pSign + (size_t)b * D + col) = make_float4(s0, s1, s2, s3);
    } else {
        const int e = b - IN_BLOCKS;
        const float4* src = reinterpret_cast<const float4*>(embed + (size_t)e * EM_ROWS * D + col);
        float4 s = make_float4(0.f, 0.f, 0.f, 0.f);
        float4 q = make_float4(0.f, 0.f, 0.f, 0.f);
        float4 v[8];
#pragma unroll
        for (int j = 0; j < 8; ++j)                     // 8 independent loads in flight
            v[j] = src[(size_t)j * (D / 4)];
#pragma unroll
        for (int j = 0; j < 8; ++j) {
            s.x += v[j].x; s.y += v[j].y; s.z += v[j].z; s.w += v[j].w;
            q.x += v[j].x * v[j].x; q.y += v[j].y * v[j].y;
            q.z += v[j].z * v[j].z; q.w += v[j].w * v[j].w;
        }
        *reinterpret_cast<float4*>(pS + (size_t)e * D + col) = s;
        *reinterpret_cast<float4*>(pQ + (size_t)e * D + col) = q;
    }
}

// K2: 512 blocks = 64 col-groups x 8 row-groups, 24 batched loads per thread.
// Level-2 partials published with relaxed AGENT atomic stores (write-through);
// __syncthreads() drains vmcnt before the ticket add. NO __threadfence —
// all-block device fences cost 40+ us on gfx950 (R4/R9 lessons).
__global__ __launch_bounds__(256) void reduce_kernel(const float* __restrict__ pSign,
                                                     const float* __restrict__ pS,
                                                     const float* __restrict__ pQ,
                                                     double* __restrict__ sgn2,
                                                     double* __restrict__ se2,
                                                     double* __restrict__ qq2,
                                                     int* __restrict__ counter,
                                                     float* __restrict__ out) {
    const int t = threadIdx.x;
    const int cg = blockIdx.x >> 3;      // 0..63
    const int rg = blockIdx.x & 7;       // 0..7
    const int c = t & 15;                // col within group
    const int g = t >> 4;                // 0..15 row stripe within rgroup
    const int d = cg * 16 + c;
    const int row0 = rg * 128 + g;       // rows row0 + k*16, k=0..7

    float vs[8], ve[8], vq[8];
#pragma unroll
    for (int k = 0; k < 8; ++k) vs[k] = pSign[(size_t)(row0 + k * 16) * D + d];
#pragma unroll
    for (int k = 0; k < 8; ++k) ve[k] = pS[(size_t)(row0 + k * 16) * D + d];
#pragma unroll
    for (int k = 0; k < 8; ++k) vq[k] = pQ[(size_t)(row0 + k * 16) * D + d];

    double sgn = 0.0, se = 0.0, qq = 0.0;
#pragma unroll
    for (int k = 0; k < 8; ++k) { sgn += (double)vs[k]; se += (double)ve[k]; qq += (double)vq[k]; }

    // fold the 4 row-stripes per wave (lanes differing by 16, 32)
    sgn += __shfl_xor(sgn, 16); sgn += __shfl_xor(sgn, 32);
    se  += __shfl_xor(se, 16);  se  += __shfl_xor(se, 32);
    qq  += __shfl_xor(qq, 16);  qq  += __shfl_xor(qq, 32);

    __shared__ double ls[3][4][16];
    const int wid = t >> 6;
    const int lane = t & 63;
    if (lane < 16) { ls[0][wid][lane] = sgn; ls[1][wid][lane] = se; ls[2][wid][lane] = qq; }
    __syncthreads();

    if (t < 16) {
        double S = ls[0][0][t] + ls[0][1][t] + ls[0][2][t] + ls[0][3][t];
        double E = ls[1][0][t] + ls[1][1][t] + ls[1][2][t] + ls[1][3][t];
        double Q = ls[2][0][t] + ls[2][1][t] + ls[2][2][t] + ls[2][3][t];
        const size_t o = (size_t)rg * D + cg * 16 + t;
        __hip_atomic_store(&sgn2[o], S, __ATOMIC_RELAXED, __HIP_MEMORY_SCOPE_AGENT);
        __hip_atomic_store(&se2[o],  E, __ATOMIC_RELAXED, __HIP_MEMORY_SCOPE_AGENT);
        __hip_atomic_store(&qq2[o],  Q, __ATOMIC_RELAXED, __HIP_MEMORY_SCOPE_AGENT);
    }
    __syncthreads();   // drains vmcnt: write-through stores complete at coherent point

    // ---- ticket: last finishing block computes the scalar ----
    __shared__ int isLast;
    if (t == 0) {
        int old = __hip_atomic_fetch_add(counter, 1, __ATOMIC_ACQ_REL,
                                         __HIP_MEMORY_SCOPE_AGENT);
        isLast = (old == GRID2 - 1);
    }
    __syncthreads();
    if (!isLast) return;

    double acc = 0.0;
#pragma unroll
    for (int rep = 0; rep < 4; ++rep) {
        const int dd = t + rep * 256;
        double S = 0.0, E = 0.0, Q = 0.0;
#pragma unroll
        for (int r = 0; r < RG; ++r) {
            S += __hip_atomic_load(&sgn2[(size_t)r * D + dd], __ATOMIC_RELAXED,
                                   __HIP_MEMORY_SCOPE_AGENT);
            E += __hip_atomic_load(&se2[(size_t)r * D + dd], __ATOMIC_RELAXED,
                                   __HIP_MEMORY_SCOPE_AGENT);
            Q += __hip_atomic_load(&qq2[(size_t)r * D + dd], __ATOMIC_RELAXED,
                                   __HIP_MEMORY_SCOPE_AGENT);
        }
        // per-column term sum: (s_e / (sqrt(M)*max(n2,eps))) * signcount
        acc += (E / (90.50966799187809 * fmax(sqrt(Q), EPS))) * S;
    }

    for (int off = 32; off > 0; off >>= 1) acc += __shfl_down(acc, off);
    __shared__ double wsum[4];
    if (lane == 0) wsum[wid] = acc;
    __syncthreads();
    if (t == 0) out[0] = (float)(wsum[0] + wsum[1] + wsum[2] + wsum[3]);
}

extern "C" void kernel_launch(void* const* d_in, const int* in_sizes, int n_in,
                              void* d_out, int out_size, void* d_ws, size_t ws_size,
                              hipStream_t stream) {
    const float* input = (const float*)d_in[0];   // [N, D]
    const float* embed = (const float*)d_in[1];   // [M, D]
    float* out = (float*)d_out;

    char* ws = (char*)d_ws;
    float* pSign = (float*)ws;                                        // 4 MB
    float* pS = pSign + (size_t)IN_BLOCKS * D;                        // 4 MB
    float* pQ = pS + (size_t)EM_BLOCKS * D;                           // 4 MB
    double* sgn2 = (double*)(pQ + (size_t)EM_BLOCKS * D);             // RG*D f64
    double* se2 = sgn2 + (size_t)RG * D;
    double* qq2 = se2 + (size_t)RG * D;
    int* counter = (int*)(qq2 + (size_t)RG * D);

    stream_kernel<<<GRID1, 256, 0, stream>>>(input, embed, pSign, pS, pQ, counter);
    reduce_kernel<<<GRID2, 256, 0, stream>>>(pSign, pS, pQ, sgn2, se2, qq2, counter, out);
}